// Round 2
// baseline (608.730 us; speedup 1.0000x reference)
//
#include <hip/hip_runtime.h>
#include <hip/hip_bf16.h>

typedef unsigned short u16;
typedef unsigned int u32;
typedef __bf16 bf16x8 __attribute__((ext_vector_type(8)));
typedef float f32x4 __attribute__((ext_vector_type(4)));
typedef u16 u16x4 __attribute__((ext_vector_type(4)));
typedef u16 u16x8 __attribute__((ext_vector_type(8)));

#define N_    4096
#define H_    16
#define BH_   64
#define DIM_  1024
#define MTOK  16384

__device__ __forceinline__ float bf2f(u16 u) {
  union { u32 i; float f; } x; x.i = ((u32)u) << 16; return x.f;
}
__device__ __forceinline__ u16 f2bf(float f) {
  union { float f; u32 i; } x; x.f = f;
  u32 r = x.i + 0x7fffu + ((x.i >> 16) & 1u);
  return (u16)(r >> 16);
}

__device__ __forceinline__ void gload_lds16(const u16* g, u16* l) {
  __builtin_amdgcn_global_load_lds(
      (const __attribute__((address_space(1))) void*)g,
      (__attribute__((address_space(3))) void*)l, 16, 0, 0);
}

// ---------------- convert hidden fp32 -> bf16 ----------------
__global__ __launch_bounds__(256) void k_hid2bf(const float* __restrict__ in,
                                                u16* __restrict__ out, int n4) {
  int i = blockIdx.x * 256 + threadIdx.x;
  if (i >= n4) return;
  f32x4 v = reinterpret_cast<const f32x4*>(in)[i];
  u16x4 o;
  o[0] = f2bf(v[0]); o[1] = f2bf(v[1]); o[2] = f2bf(v[2]); o[3] = f2bf(v[3]);
  reinterpret_cast<u16x4*>(out)[i] = o;
}

// ---------------- transpose W [k][n] -> Wt bf16 [n][k], 3 weights ----------------
__global__ __launch_bounds__(256) void k_transpose(const float* __restrict__ Wq,
                                                   const float* __restrict__ Wk,
                                                   const float* __restrict__ Wv,
                                                   u16* __restrict__ Wt) {
  __shared__ float tile[32][33];
  const float* W = (blockIdx.z == 0) ? Wq : ((blockIdx.z == 1) ? Wk : Wv);
  int n0 = blockIdx.x * 32, k0 = blockIdx.y * 32;
  int tx = threadIdx.x, ty = threadIdx.y;
  #pragma unroll
  for (int r = ty; r < 32; r += 8)
    tile[r][tx] = W[(size_t)(k0 + r) * DIM_ + n0 + tx];
  __syncthreads();
  u16* o = Wt + (size_t)blockIdx.z * DIM_ * DIM_;
  #pragma unroll
  for (int r = ty; r < 32; r += 8)
    o[(size_t)(n0 + r) * DIM_ + k0 + tx] = f2bf(tile[tx][r]);
}

// ---------------- fused QKV GEMM (m97 structure: 128x128 tile, BK=32) ----------------
// C[m, n] = sum_k hid[m,k] * W[k,n] + bias[n]; output to bf16 head-split [bh][pos][64]
__global__ __launch_bounds__(256) void k_qkv_gemm(
    const u16* __restrict__ hid,   // [16384][1024] bf16
    const u16* __restrict__ Wt,    // [3][1024][1024] bf16, n-major (W^T)
    const float* __restrict__ bq, const float* __restrict__ bk, const float* __restrict__ bv,
    u16* __restrict__ qout, u16* __restrict__ kout, u16* __restrict__ vout) {
  const int wsel = blockIdx.z;
  const int m0 = blockIdx.x * 128;
  const int n0 = blockIdx.y * 128;
  __shared__ u16 As[128 * 32];
  __shared__ u16 Bs[128 * 32];
  const int t = threadIdx.x;
  const int lane = t & 63, wave = t >> 6;
  const int wm = (wave >> 1) * 64, wn = (wave & 1) * 64;
  f32x4 acc[4][4];
  #pragma unroll
  for (int m = 0; m < 4; m++)
    #pragma unroll
    for (int n = 0; n < 4; n++) acc[m][n] = (f32x4){0.f, 0.f, 0.f, 0.f};

  const u16* Ag = hid + (size_t)m0 * DIM_;
  const u16* Bg = Wt + (size_t)wsel * DIM_ * DIM_ + (size_t)n0 * DIM_;
  const int l0 = t, l1 = t + 256;
  const int ar0 = l0 >> 2, ac0 = (l0 & 3) * 8;
  const int ar1 = l1 >> 2, ac1 = (l1 & 3) * 8;
  const int lr = lane & 15, kg = lane >> 4;

  for (int k0 = 0; k0 < DIM_; k0 += 32) {
    gload_lds16(Ag + (size_t)ar0 * DIM_ + k0 + ac0, &As[l0 * 8]);
    gload_lds16(Ag + (size_t)ar1 * DIM_ + k0 + ac1, &As[l1 * 8]);
    gload_lds16(Bg + (size_t)ar0 * DIM_ + k0 + ac0, &Bs[l0 * 8]);
    gload_lds16(Bg + (size_t)ar1 * DIM_ + k0 + ac1, &Bs[l1 * 8]);
    __syncthreads();
    bf16x8 af[4], bfr[4];
    #pragma unroll
    for (int m = 0; m < 4; m++)
      af[m] = *reinterpret_cast<const bf16x8*>(&As[(wm + m * 16 + lr) * 32 + kg * 8]);
    #pragma unroll
    for (int n = 0; n < 4; n++)
      bfr[n] = *reinterpret_cast<const bf16x8*>(&Bs[(wn + n * 16 + lr) * 32 + kg * 8]);
    #pragma unroll
    for (int m = 0; m < 4; m++)
      #pragma unroll
      for (int n = 0; n < 4; n++)
        acc[m][n] = __builtin_amdgcn_mfma_f32_16x16x32_bf16(af[m], bfr[n], acc[m][n], 0, 0, 0);
    __syncthreads();
  }

  const float* bias = (wsel == 0) ? bq : ((wsel == 1) ? bk : bv);
  u16* dst = (wsel == 0) ? qout : ((wsel == 1) ? kout : vout);
  const float scale = (wsel == 0) ? 0.125f : 1.0f;  // DH^-0.5 = 1/8
  const int rg = lane >> 4;
  #pragma unroll
  for (int m = 0; m < 4; m++) {
    #pragma unroll
    for (int n = 0; n < 4; n++) {
      int col = n0 + wn + n * 16 + lr;        // 0..1023 (output feature)
      float bias_v = bias[col];
      int h = col >> 6, d = col & 63;
      #pragma unroll
      for (int i = 0; i < 4; i++) {
        int row = m0 + wm + m * 16 + rg * 4 + i;  // token 0..16383
        int b = row >> 12, pos = row & (N_ - 1);
        float v = (acc[m][n][i] + bias_v) * scale;
        dst[(((size_t)(b * H_ + h) * N_ + pos) << 6) + d] = f2bf(v);
      }
    }
  }
}

// ---------------- coarsen one level (q,k mean; v sum) ----------------
__global__ __launch_bounds__(256) void k_coarsen(u16* __restrict__ qb, u16* __restrict__ kb,
                                                 u16* __restrict__ vb,
                                                 int rowsInBase, int rowsOutBase, int lnl) {
  const int nl = 1 << lnl;
  int tid = blockIdx.x * 256 + threadIdx.x;
  if (tid >= BH_ * nl * 16) return;
  int dg = tid & 15;
  int p = (tid >> 4) & (nl - 1);
  int bh = tid >> (4 + lnl);
  u16* buf = (blockIdx.z == 0) ? qb : ((blockIdx.z == 1) ? kb : vb);
  float s = (blockIdx.z == 2) ? 1.0f : 0.5f;
  size_t rin = ((size_t)rowsInBase + (size_t)bh * (nl * 2) + 2 * p) * 64 + dg * 4;
  size_t rout = ((size_t)rowsOutBase + (size_t)bh * nl + p) * 64 + dg * 4;
  u16x4 a = *reinterpret_cast<const u16x4*>(&buf[rin]);
  u16x4 b = *reinterpret_cast<const u16x4*>(&buf[rin + 64]);
  u16x4 o;
  #pragma unroll
  for (int j = 0; j < 4; j++) o[j] = f2bf((bf2f(a[j]) + bf2f(b[j])) * s);
  *reinterpret_cast<u16x4*>(&buf[rout]) = o;
}

// ---------------- per-level block attention ----------------
// one thread = one output row; S = q_row . k_rows(16), A = exp(S-max), Y = A.V, Asum
__global__ __launch_bounds__(256) void k_attn(
    const u16* __restrict__ qb, const u16* __restrict__ kb, const u16* __restrict__ vb,
    u16* __restrict__ Yb, float* __restrict__ Ab, float* __restrict__ outY,
    int level, int lnl, int rowBase, int yRowBase) {
  const int nl = 1 << lnl;
  int gid = blockIdx.x * 256 + threadIdx.x;
  if (gid >= BH_ * nl) return;
  int bh = gid >> lnl;
  int pos = gid & (nl - 1);
  int blk = pos >> 4;
  int kvblk = (level == 0) ? blk : (blk ^ 1);
  size_t qrow = ((size_t)rowBase + (size_t)bh * nl + pos) * 64;
  size_t kvrow = ((size_t)rowBase + (size_t)bh * nl + (size_t)kvblk * 16) * 64;

  float q[64];
  #pragma unroll
  for (int j = 0; j < 8; j++) {
    u16x8 tq = *reinterpret_cast<const u16x8*>(&qb[qrow + j * 8]);
    #pragma unroll
    for (int e = 0; e < 8; e++) q[j * 8 + e] = bf2f(tq[e]);
  }

  float S[16];
  float mx = -3.4e38f;
  #pragma unroll
  for (int c = 0; c < 16; c++) {
    float s = 0.f;
    #pragma unroll
    for (int j = 0; j < 8; j++) {
      u16x8 tk = *reinterpret_cast<const u16x8*>(&kb[kvrow + c * 64 + j * 8]);
      #pragma unroll
      for (int e = 0; e < 8; e++) s += q[j * 8 + e] * bf2f(tk[e]);
    }
    S[c] = s;
    mx = fmaxf(mx, s);
  }
  float asum = 0.f;
  #pragma unroll
  for (int c = 0; c < 16; c++) { S[c] = __expf(S[c] - mx); asum += S[c]; }

  float* yrow_f = nullptr;
  u16* yrow_b = nullptr;
  if (level == 0) {
    int b = bh >> 4, h = bh & 15;
    yrow_f = outY + ((size_t)(b * N_ + pos)) * DIM_ + h * 64;
  } else {
    yrow_b = Yb + ((size_t)yRowBase + (size_t)bh * nl + pos) * 64;
  }
  #pragma unroll
  for (int d0 = 0; d0 < 64; d0 += 8) {
    float y[8] = {0, 0, 0, 0, 0, 0, 0, 0};
    #pragma unroll
    for (int c = 0; c < 16; c++) {
      u16x8 tv = *reinterpret_cast<const u16x8*>(&vb[kvrow + c * 64 + d0]);
      #pragma unroll
      for (int e = 0; e < 8; e++) y[e] += S[c] * bf2f(tv[e]);
    }
    if (level == 0) {
      #pragma unroll
      for (int e = 0; e < 8; e++) yrow_f[d0 + e] = y[e];
    } else {
      u16x8 o;
      #pragma unroll
      for (int e = 0; e < 8; e++) o[e] = f2bf(y[e]);
      *reinterpret_cast<u16x8*>(&yrow_b[d0]) = o;
    }
  }
  Ab[(size_t)rowBase + (size_t)bh * nl + pos] = asum;
}

// ---------------- combine levels: out = sum_l Y_l[t>>l] / (sum_l A_l[t>>l] + eps) ----------------
__global__ __launch_bounds__(256) void k_combine(const u16* __restrict__ Yb,
                                                 const float* __restrict__ Ab,
                                                 float* __restrict__ out) {
  int gid = blockIdx.x * 256 + threadIdx.x;  // 2^24 threads
  int d = gid & 63;
  int pos = (gid >> 6) & (N_ - 1);
  int bh = gid >> 18;
  const int CUMN[7] = {0, 4096, 6144, 7168, 7680, 7936, 8064};
  float asum = 0.f;
  #pragma unroll
  for (int l = 0; l < 7; l++) {
    int nl = N_ >> l;
    asum += Ab[(size_t)CUMN[l] * 64 + (size_t)bh * nl + (pos >> l)];
  }
  int b = bh >> 4, h = bh & 15;
  size_t oidx = ((size_t)(b * N_ + pos)) * DIM_ + h * 64 + d;
  float y = out[oidx];  // level-0 Y was written here by k_attn
  #pragma unroll
  for (int l = 1; l < 7; l++) {
    int nl = N_ >> l;
    y += bf2f(Yb[(((size_t)(CUMN[l] - 4096) * 64) + (size_t)bh * nl + (pos >> l)) * 64 + d]);
  }
  out[oidx] = y / (asum + 1e-8f);
}

extern "C" void kernel_launch(void* const* d_in, const int* in_sizes, int n_in,
                              void* d_out, int out_size, void* d_ws, size_t ws_size,
                              hipStream_t stream) {
  const float* hid = (const float*)d_in[0];
  const float* Wq = (const float*)d_in[1];
  const float* bq = (const float*)d_in[2];
  const float* Wk = (const float*)d_in[3];
  const float* bk = (const float*)d_in[4];
  const float* Wv = (const float*)d_in[5];
  const float* bv = (const float*)d_in[6];
  float* out = (float*)d_out;
  char* ws = (char*)d_ws;

  // workspace layout (bytes), total high-water 239,599,616 (228.5 MB):
  //   phase 1 (GEMM):      hidb [0, 33554432)  Wt [33554432, 39845888)
  //   phase 2 (attention): Yb   [0, 33030144)  Ab [33030144, 35110912)   <- aliases hidb/Wt (dead)
  //   both phases:         qb [39845888, ...)  kb, vb
  u16* hidb = (u16*)(ws + 0);
  u16* Wt   = (u16*)(ws + 33554432);
  u16* Yb   = (u16*)(ws + 0);            // bf16, levels 1..6 (64bh x 4032 rows x 64)
  float* Ab = (float*)(ws + 33030144);   // fp32, levels 0..6 (64bh x 8128 rows)
  u16* qb   = (u16*)(ws + 39845888);     // 66,584,576 (levels 0..6)
  u16* kb   = (u16*)(ws + 106430464);
  u16* vb   = (u16*)(ws + 173015040);    // ends 239,599,616

  k_hid2bf<<<16384, 256, 0, stream>>>(hid, hidb, MTOK * DIM_ / 4);
  k_transpose<<<dim3(32, 32, 3), dim3(32, 8, 1), 0, stream>>>(Wq, Wk, Wv, Wt);
  k_qkv_gemm<<<dim3(128, 8, 3), 256, 0, stream>>>(hidb, Wt, bq, bk, bv, qb, kb, vb);

  const int cumn[8] = {0, 4096, 6144, 7168, 7680, 7936, 8064, 8128};
  for (int l = 1; l <= 6; l++) {
    int lnl = 12 - l;
    int nl = 1 << lnl;
    int total = BH_ * nl * 16;
    k_coarsen<<<dim3((total + 255) / 256, 1, 3), 256, 0, stream>>>(
        qb, kb, vb, 64 * cumn[l - 1], 64 * cumn[l], lnl);
  }
  for (int l = 0; l <= 6; l++) {
    int lnl = 12 - l;
    int nl = 1 << lnl;
    int total = BH_ * nl;
    k_attn<<<(total + 255) / 256, 256, 0, stream>>>(
        qb, kb, vb, Yb, Ab, out, l, lnl, 64 * cumn[l],
        (l >= 1) ? 64 * (cumn[l] - 4096) : 0);
  }
  k_combine<<<65536, 256, 0, stream>>>(Yb, Ab, out);
}

// Round 3
// 325.391 us; speedup vs baseline: 1.8708x; 1.8708x over previous
//
#include <hip/hip_runtime.h>
#include <hip/hip_bf16.h>

typedef unsigned short u16;
typedef unsigned int u32;
typedef __bf16 bf16x8 __attribute__((ext_vector_type(8)));
typedef float f32x4 __attribute__((ext_vector_type(4)));
typedef u16 u16x4 __attribute__((ext_vector_type(4)));
typedef u16 u16x8 __attribute__((ext_vector_type(8)));

#define N_    4096
#define H_    16
#define BH_   64
#define DIM_  1024
#define MTOK  16384

// global row bases (row = 64 bf16 elements): 64*cumn[l]
// L0:0  L1:262144  L2:393216  L3:458752  L4:491520  L5:507904  L6:516096  end:520192
#define RB1 262144
#define RB2 393216
#define RB3 458752
#define RB4 491520
#define RB5 507904
#define RB6 516096

__device__ __forceinline__ float bf2f(u16 u) {
  union { u32 i; float f; } x; x.i = ((u32)u) << 16; return x.f;
}
__device__ __forceinline__ u16 f2bf(float f) {
  union { float f; u32 i; } x; x.f = f;
  u32 r = x.i + 0x7fffu + ((x.i >> 16) & 1u);
  return (u16)(r >> 16);
}

__device__ __forceinline__ void gload_lds16(const u16* g, u16* l) {
  __builtin_amdgcn_global_load_lds(
      (const __attribute__((address_space(1))) void*)g,
      (__attribute__((address_space(3))) void*)l, 16, 0, 0);
}

// ---------------- convert hidden fp32 -> bf16 ----------------
__global__ __launch_bounds__(256) void k_hid2bf(const float* __restrict__ in,
                                                u16* __restrict__ out, int n4) {
  int i = blockIdx.x * 256 + threadIdx.x;
  if (i >= n4) return;
  f32x4 v = reinterpret_cast<const f32x4*>(in)[i];
  u16x4 o;
  o[0] = f2bf(v[0]); o[1] = f2bf(v[1]); o[2] = f2bf(v[2]); o[3] = f2bf(v[3]);
  reinterpret_cast<u16x4*>(out)[i] = o;
}

// ---------------- transpose W [k][n] -> Wt bf16 [n][k], 3 weights ----------------
__global__ __launch_bounds__(256) void k_transpose(const float* __restrict__ Wq,
                                                   const float* __restrict__ Wk,
                                                   const float* __restrict__ Wv,
                                                   u16* __restrict__ Wt) {
  __shared__ float tile[32][33];
  const float* W = (blockIdx.z == 0) ? Wq : ((blockIdx.z == 1) ? Wk : Wv);
  int n0 = blockIdx.x * 32, k0 = blockIdx.y * 32;
  int tx = threadIdx.x, ty = threadIdx.y;
  #pragma unroll
  for (int r = ty; r < 32; r += 8)
    tile[r][tx] = W[(size_t)(k0 + r) * DIM_ + n0 + tx];
  __syncthreads();
  u16* o = Wt + (size_t)blockIdx.z * DIM_ * DIM_;
  #pragma unroll
  for (int r = ty; r < 32; r += 8)
    o[(size_t)(n0 + r) * DIM_ + k0 + tx] = f2bf(tile[tx][r]);
}

// ---------------- fused QKV GEMM (m97 structure: 128x128 tile, BK=32) ----------------
__global__ __launch_bounds__(256) void k_qkv_gemm(
    const u16* __restrict__ hid,   // [16384][1024] bf16
    const u16* __restrict__ Wt,    // [3][1024][1024] bf16, n-major (W^T)
    const float* __restrict__ bq, const float* __restrict__ bk, const float* __restrict__ bv,
    u16* __restrict__ qout, u16* __restrict__ kout, u16* __restrict__ vout) {
  const int wsel = blockIdx.z;
  const int m0 = blockIdx.x * 128;
  const int n0 = blockIdx.y * 128;
  __shared__ u16 As[128 * 32];
  __shared__ u16 Bs[128 * 32];
  const int t = threadIdx.x;
  const int lane = t & 63, wave = t >> 6;
  const int wm = (wave >> 1) * 64, wn = (wave & 1) * 64;
  f32x4 acc[4][4];
  #pragma unroll
  for (int m = 0; m < 4; m++)
    #pragma unroll
    for (int n = 0; n < 4; n++) acc[m][n] = (f32x4){0.f, 0.f, 0.f, 0.f};

  const u16* Ag = hid + (size_t)m0 * DIM_;
  const u16* Bg = Wt + (size_t)wsel * DIM_ * DIM_ + (size_t)n0 * DIM_;
  const int l0 = t, l1 = t + 256;
  const int ar0 = l0 >> 2, ac0 = (l0 & 3) * 8;
  const int ar1 = l1 >> 2, ac1 = (l1 & 3) * 8;
  const int lr = lane & 15, kg = lane >> 4;

  for (int k0 = 0; k0 < DIM_; k0 += 32) {
    gload_lds16(Ag + (size_t)ar0 * DIM_ + k0 + ac0, &As[l0 * 8]);
    gload_lds16(Ag + (size_t)ar1 * DIM_ + k0 + ac1, &As[l1 * 8]);
    gload_lds16(Bg + (size_t)ar0 * DIM_ + k0 + ac0, &Bs[l0 * 8]);
    gload_lds16(Bg + (size_t)ar1 * DIM_ + k0 + ac1, &Bs[l1 * 8]);
    __syncthreads();
    bf16x8 af[4], bfr[4];
    #pragma unroll
    for (int m = 0; m < 4; m++)
      af[m] = *reinterpret_cast<const bf16x8*>(&As[(wm + m * 16 + lr) * 32 + kg * 8]);
    #pragma unroll
    for (int n = 0; n < 4; n++)
      bfr[n] = *reinterpret_cast<const bf16x8*>(&Bs[(wn + n * 16 + lr) * 32 + kg * 8]);
    #pragma unroll
    for (int m = 0; m < 4; m++)
      #pragma unroll
      for (int n = 0; n < 4; n++)
        acc[m][n] = __builtin_amdgcn_mfma_f32_16x16x32_bf16(af[m], bfr[n], acc[m][n], 0, 0, 0);
    __syncthreads();
  }

  const float* bias = (wsel == 0) ? bq : ((wsel == 1) ? bk : bv);
  u16* dst = (wsel == 0) ? qout : ((wsel == 1) ? kout : vout);
  const float scale = (wsel == 0) ? 0.125f : 1.0f;  // DH^-0.5 = 1/8
  const int rg = lane >> 4;
  #pragma unroll
  for (int m = 0; m < 4; m++) {
    #pragma unroll
    for (int n = 0; n < 4; n++) {
      int col = n0 + wn + n * 16 + lr;
      float bias_v = bias[col];
      int h = col >> 6, d = col & 63;
      #pragma unroll
      for (int i = 0; i < 4; i++) {
        int row = m0 + wm + m * 16 + rg * 4 + i;
        int b = row >> 12, pos = row & (N_ - 1);
        float v = (acc[m][n][i] + bias_v) * scale;
        dst[(((size_t)(b * H_ + h) * N_ + pos) << 6) + d] = f2bf(v);
      }
    }
  }
}

// ---------------- coarsen pass 1: levels 1..4 directly from level 0 ----------------
// thread = (z, bh, p4, dg): reads 16 L0 rows (one 8-elem d-chunk), carry-chain tree
__global__ __launch_bounds__(256) void k_coarsen14(u16* __restrict__ qb, u16* __restrict__ kb,
                                                   u16* __restrict__ vb) {
  int t = blockIdx.x * 256 + threadIdx.x;  // 3*64*256*8 = 393216
  int dg = t & 7;
  int p4 = (t >> 3) & 255;
  int bh = (t >> 11) & 63;
  int z = t >> 17;
  u16* buf = (z == 0) ? qb : ((z == 1) ? kb : vb);
  const bool isv = (z == 2);
  const float s1 = isv ? 1.f : 0.5f, s2 = isv ? 1.f : 0.25f;
  const float s3 = isv ? 1.f : 0.125f, s4 = isv ? 1.f : 0.0625f;
  const u16* src = buf + ((size_t)bh * 4096 + p4 * 16) * 64 + dg * 8;
  float a1[8], a2[8], a3[8], a4[8];
  #pragma unroll
  for (int e = 0; e < 8; e++) { a1[e] = 0.f; a2[e] = 0.f; a3[e] = 0.f; a4[e] = 0.f; }
  #pragma unroll
  for (int i = 0; i < 16; i++) {
    u16x8 x = *reinterpret_cast<const u16x8*>(src + (size_t)i * 64);
    #pragma unroll
    for (int e = 0; e < 8; e++) a1[e] += bf2f(x[e]);
    if ((i & 1) == 1) {
      u16x8 o;
      #pragma unroll
      for (int e = 0; e < 8; e++) { o[e] = f2bf(a1[e] * s1); a2[e] += a1[e]; a1[e] = 0.f; }
      *reinterpret_cast<u16x8*>(buf + ((size_t)RB1 + bh * 2048 + p4 * 8 + (i >> 1)) * 64 + dg * 8) = o;
    }
    if ((i & 3) == 3) {
      u16x8 o;
      #pragma unroll
      for (int e = 0; e < 8; e++) { o[e] = f2bf(a2[e] * s2); a3[e] += a2[e]; a2[e] = 0.f; }
      *reinterpret_cast<u16x8*>(buf + ((size_t)RB2 + bh * 1024 + p4 * 4 + (i >> 2)) * 64 + dg * 8) = o;
    }
    if ((i & 7) == 7) {
      u16x8 o;
      #pragma unroll
      for (int e = 0; e < 8; e++) { o[e] = f2bf(a3[e] * s3); a4[e] += a3[e]; a3[e] = 0.f; }
      *reinterpret_cast<u16x8*>(buf + ((size_t)RB3 + bh * 512 + p4 * 2 + (i >> 3)) * 64 + dg * 8) = o;
    }
  }
  u16x8 o;
  #pragma unroll
  for (int e = 0; e < 8; e++) o[e] = f2bf(a4[e] * s4);
  *reinterpret_cast<u16x8*>(buf + ((size_t)RB4 + bh * 256 + p4) * 64 + dg * 8) = o;
}

// ---------------- coarsen pass 2: levels 5..6 from level 4 ----------------
__global__ __launch_bounds__(256) void k_coarsen56(u16* __restrict__ qb, u16* __restrict__ kb,
                                                   u16* __restrict__ vb) {
  int t = blockIdx.x * 256 + threadIdx.x;  // 3*64*64*8 = 98304
  int dg = t & 7;
  int p6 = (t >> 3) & 63;
  int bh = (t >> 9) & 63;
  int z = t >> 15;
  u16* buf = (z == 0) ? qb : ((z == 1) ? kb : vb);
  const bool isv = (z == 2);
  const float s5 = isv ? 1.f : 0.5f, s6 = isv ? 1.f : 0.25f;
  const u16* src = buf + ((size_t)RB4 + bh * 256 + p6 * 4) * 64 + dg * 8;
  float a5[8], a6[8];
  #pragma unroll
  for (int e = 0; e < 8; e++) { a5[e] = 0.f; a6[e] = 0.f; }
  #pragma unroll
  for (int i = 0; i < 4; i++) {
    u16x8 x = *reinterpret_cast<const u16x8*>(src + (size_t)i * 64);
    #pragma unroll
    for (int e = 0; e < 8; e++) a5[e] += bf2f(x[e]);
    if ((i & 1) == 1) {
      u16x8 o;
      #pragma unroll
      for (int e = 0; e < 8; e++) { o[e] = f2bf(a5[e] * s5); a6[e] += a5[e]; a5[e] = 0.f; }
      *reinterpret_cast<u16x8*>(buf + ((size_t)RB5 + bh * 128 + p6 * 2 + (i >> 1)) * 64 + dg * 8) = o;
    }
  }
  u16x8 o;
  #pragma unroll
  for (int e = 0; e < 8; e++) o[e] = f2bf(a6[e] * s6);
  *reinterpret_cast<u16x8*>(buf + ((size_t)RB6 + bh * 64 + p6) * 64 + dg * 8) = o;
}

// ---------------- shared attention core: S = q . K^T (16), A = exp(S - max) ----------------
__device__ __forceinline__ void block_scores(const u16* __restrict__ qp,
                                             const u16* __restrict__ kp,
                                             float* A, float& asum) {
  u16x8 q8[8];
  #pragma unroll
  for (int j = 0; j < 8; j++) q8[j] = *reinterpret_cast<const u16x8*>(qp + j * 8);
  float mx = -3.4e38f;
  #pragma unroll
  for (int c = 0; c < 16; c++) {
    float s = 0.f;
    #pragma unroll
    for (int j = 0; j < 8; j++) {
      u16x8 k8 = *reinterpret_cast<const u16x8*>(kp + c * 64 + j * 8);
      #pragma unroll
      for (int e = 0; e < 8; e++) s += bf2f(q8[j][e]) * bf2f(k8[e]);
    }
    A[c] = s;
    mx = fmaxf(mx, s);
  }
  asum = 0.f;
  #pragma unroll
  for (int c = 0; c < 16; c++) { A[c] = __expf(A[c] - mx); asum += A[c]; }
}

// ---------------- attention levels 1..6, one launch ----------------
// rows for levels 1..6 are contiguous from RB1: global row = RB1 + gid
__global__ __launch_bounds__(256) void k_attn_rest(
    const u16* __restrict__ qb, const u16* __restrict__ kb, const u16* __restrict__ vb,
    u16* __restrict__ Yb, float* __restrict__ Ab) {
  int gid = blockIdx.x * 256 + threadIdx.x;  // 258048 = 1008*256 exactly
  int r = gid, lnl = 11;
  while (r >= (64 << lnl)) { r -= (64 << lnl); --lnl; }
  int pos = r & ((1 << lnl) - 1);
  size_t row = (size_t)RB1 + gid;
  size_t kvrow = row - pos + ((((pos >> 4) ^ 1) & ((1 << (lnl - 4)) - 1)) << 4);

  float A[16], asum;
  block_scores(qb + row * 64, kb + kvrow * 64, A, asum);
  Ab[gid] = asum;

  const u16* vp = vb + kvrow * 64;
  u16* yp = Yb + (size_t)gid * 64;
  #pragma unroll
  for (int d0 = 0; d0 < 64; d0 += 16) {
    float y[16];
    #pragma unroll
    for (int e = 0; e < 16; e++) y[e] = 0.f;
    #pragma unroll
    for (int c = 0; c < 16; c++) {
      u16x8 v0 = *reinterpret_cast<const u16x8*>(vp + c * 64 + d0);
      u16x8 v1 = *reinterpret_cast<const u16x8*>(vp + c * 64 + d0 + 8);
      float a = A[c];
      #pragma unroll
      for (int e = 0; e < 8; e++) { y[e] += a * bf2f(v0[e]); y[8 + e] += a * bf2f(v1[e]); }
    }
    u16x8 o0, o1;
    #pragma unroll
    for (int e = 0; e < 8; e++) { o0[e] = f2bf(y[e]); o1[e] = f2bf(y[8 + e]); }
    *reinterpret_cast<u16x8*>(yp + d0) = o0;
    *reinterpret_cast<u16x8*>(yp + d0 + 8) = o1;
  }
}

// ---------------- attention level 0 fused with combine ----------------
__global__ __launch_bounds__(256) void k_attn0(
    const u16* __restrict__ qb, const u16* __restrict__ kb, const u16* __restrict__ vb,
    const u16* __restrict__ Yb, const float* __restrict__ Ab, float* __restrict__ out) {
  int gid = blockIdx.x * 256 + threadIdx.x;  // 262144 = 1024*256
  int bh = gid >> 12, pos = gid & 4095;
  size_t row = (size_t)gid;
  size_t kvrow = row - (pos & 15);  // level 0: diagonal block

  float A[16], asum;
  block_scores(qb + row * 64, kb + kvrow * 64, A, asum);

  float den = asum + 1e-8f;
  int ybase[6];
  #pragma unroll
  for (int l = 1; l <= 6; l++) {
    int s = 262144 - (262144 >> (l - 1));  // packed level-l segment start
    int idx = s + (bh << (12 - l)) + (pos >> l);
    den += Ab[idx];
    ybase[l - 1] = idx;
  }
  float inv = 1.0f / den;

  int b = bh >> 4, h = bh & 15;
  float* op = out + ((size_t)(b * N_ + pos)) * DIM_ + h * 64;
  const u16* vp = vb + kvrow * 64;
  #pragma unroll
  for (int d0 = 0; d0 < 64; d0 += 16) {
    float y[16];
    #pragma unroll
    for (int e = 0; e < 16; e++) y[e] = 0.f;
    #pragma unroll
    for (int c = 0; c < 16; c++) {
      u16x8 v0 = *reinterpret_cast<const u16x8*>(vp + c * 64 + d0);
      u16x8 v1 = *reinterpret_cast<const u16x8*>(vp + c * 64 + d0 + 8);
      float a = A[c];
      #pragma unroll
      for (int e = 0; e < 8; e++) { y[e] += a * bf2f(v0[e]); y[8 + e] += a * bf2f(v1[e]); }
    }
    #pragma unroll
    for (int l = 0; l < 6; l++) {
      const u16* yq = Yb + (size_t)ybase[l] * 64 + d0;
      u16x8 c0 = *reinterpret_cast<const u16x8*>(yq);
      u16x8 c1 = *reinterpret_cast<const u16x8*>(yq + 8);
      #pragma unroll
      for (int e = 0; e < 8; e++) { y[e] += bf2f(c0[e]); y[8 + e] += bf2f(c1[e]); }
    }
    f32x4 w0, w1, w2, w3;
    #pragma unroll
    for (int e = 0; e < 4; e++) {
      w0[e] = y[e] * inv; w1[e] = y[4 + e] * inv;
      w2[e] = y[8 + e] * inv; w3[e] = y[12 + e] * inv;
    }
    *reinterpret_cast<f32x4*>(op + d0) = w0;
    *reinterpret_cast<f32x4*>(op + d0 + 4) = w1;
    *reinterpret_cast<f32x4*>(op + d0 + 8) = w2;
    *reinterpret_cast<f32x4*>(op + d0 + 12) = w3;
  }
}

extern "C" void kernel_launch(void* const* d_in, const int* in_sizes, int n_in,
                              void* d_out, int out_size, void* d_ws, size_t ws_size,
                              hipStream_t stream) {
  const float* hid = (const float*)d_in[0];
  const float* Wq = (const float*)d_in[1];
  const float* bq = (const float*)d_in[2];
  const float* Wk = (const float*)d_in[3];
  const float* bk = (const float*)d_in[4];
  const float* Wv = (const float*)d_in[5];
  const float* bv = (const float*)d_in[6];
  float* out = (float*)d_out;
  char* ws = (char*)d_ws;

  // workspace (high-water 239,599,616 B):
  //   phase 1 (GEMM):  hidb [0, 33554432)   Wt [33554432, 39845888)
  //   phase 2 (attn):  Yb   [0, 33030144)   Ab [33030144, 34062336)   <- aliases dead hidb/Wt
  //   both:            qb [39845888) kb [106430464) vb [173015040) .. 239599616
  u16* hidb = (u16*)(ws + 0);
  u16* Wt   = (u16*)(ws + 33554432);
  u16* Yb   = (u16*)(ws + 0);           // bf16, levels 1..6 packed (258048 rows x 64)
  float* Ab = (float*)(ws + 33030144);  // fp32, levels 1..6 packed (258048)
  u16* qb   = (u16*)(ws + 39845888);
  u16* kb   = (u16*)(ws + 106430464);
  u16* vb   = (u16*)(ws + 173015040);

  k_hid2bf<<<16384, 256, 0, stream>>>(hid, hidb, MTOK * DIM_ / 4);
  k_transpose<<<dim3(32, 32, 3), dim3(32, 8, 1), 0, stream>>>(Wq, Wk, Wv, Wt);
  k_qkv_gemm<<<dim3(128, 8, 3), 256, 0, stream>>>(hidb, Wt, bq, bk, bv, qb, kb, vb);
  k_coarsen14<<<1536, 256, 0, stream>>>(qb, kb, vb);
  k_coarsen56<<<384, 256, 0, stream>>>(qb, kb, vb);
  k_attn_rest<<<1008, 256, 0, stream>>>(qb, kb, vb, Yb, Ab);
  k_attn0<<<1024, 256, 0, stream>>>(qb, kb, vb, Yb, Ab, out);
}

// Round 4
// 299.933 us; speedup vs baseline: 2.0296x; 1.0849x over previous
//
#include <hip/hip_runtime.h>
#include <hip/hip_bf16.h>

typedef unsigned short u16;
typedef unsigned int u32;
typedef __bf16 bf16x8 __attribute__((ext_vector_type(8)));
typedef float f32x4 __attribute__((ext_vector_type(4)));
typedef u16 u16x4 __attribute__((ext_vector_type(4)));
typedef u16 u16x8 __attribute__((ext_vector_type(8)));

#define N_    4096
#define H_    16
#define BH_   64
#define DIM_  1024
#define MTOK  16384

// global row bases (row = 64 bf16 elements): 64*cumn[l]
#define RB1 262144
#define RB2 393216
#define RB3 458752
#define RB4 491520
#define RB5 507904
#define RB6 516096

__device__ __forceinline__ float bf2f(u16 u) {
  union { u32 i; float f; } x; x.i = ((u32)u) << 16; return x.f;
}
__device__ __forceinline__ u16 f2bf(float f) {
  union { float f; u32 i; } x; x.f = f;
  u32 r = x.i + 0x7fffu + ((x.i >> 16) & 1u);
  return (u16)(r >> 16);
}

__device__ __forceinline__ void gload_lds16(const u16* g, u16* l) {
  __builtin_amdgcn_global_load_lds(
      (const __attribute__((address_space(1))) void*)g,
      (__attribute__((address_space(3))) void*)l, 16, 0, 0);
}

// ---------------- convert hidden fp32 -> bf16 ----------------
__global__ __launch_bounds__(256) void k_hid2bf(const float* __restrict__ in,
                                                u16* __restrict__ out, int n4) {
  int i = blockIdx.x * 256 + threadIdx.x;
  if (i >= n4) return;
  f32x4 v = reinterpret_cast<const f32x4*>(in)[i];
  u16x4 o;
  o[0] = f2bf(v[0]); o[1] = f2bf(v[1]); o[2] = f2bf(v[2]); o[3] = f2bf(v[3]);
  reinterpret_cast<u16x4*>(out)[i] = o;
}

// ---------------- transpose W [k][n] -> Wt bf16 [n][k], 3 weights ----------------
__global__ __launch_bounds__(256) void k_transpose(const float* __restrict__ Wq,
                                                   const float* __restrict__ Wk,
                                                   const float* __restrict__ Wv,
                                                   u16* __restrict__ Wt) {
  __shared__ float tile[32][33];
  const float* W = (blockIdx.z == 0) ? Wq : ((blockIdx.z == 1) ? Wk : Wv);
  int n0 = blockIdx.x * 32, k0 = blockIdx.y * 32;
  int tx = threadIdx.x, ty = threadIdx.y;
  #pragma unroll
  for (int r = ty; r < 32; r += 8)
    tile[r][tx] = W[(size_t)(k0 + r) * DIM_ + n0 + tx];
  __syncthreads();
  u16* o = Wt + (size_t)blockIdx.z * DIM_ * DIM_;
  #pragma unroll
  for (int r = ty; r < 32; r += 8)
    o[(size_t)(n0 + r) * DIM_ + k0 + tx] = f2bf(tile[tx][r]);
}

// ---------------- fused QKV GEMM, BK=64, T2-swizzled LDS, coarsen L1-L4 in epilogue ----
// LDS tile: logical [128 rows][64 k] u16 (128B row = 32 banks); physical slot = logical ^ (row&7)
// Staging: global_load_lds dest is linear (base + lane*16); swizzle achieved by pre-swizzling
// the per-lane GLOBAL source slot (rule #21 / m173).
__global__ __launch_bounds__(256) void k_qkv_gemm(
    const u16* __restrict__ hid,   // [16384][1024] bf16
    const u16* __restrict__ Wt,    // [3][1024][1024] bf16, n-major (W^T)
    const float* __restrict__ bq, const float* __restrict__ bk, const float* __restrict__ bv,
    u16* __restrict__ qout, u16* __restrict__ kout, u16* __restrict__ vout) {
  const int wsel = blockIdx.z;
  const int m0 = blockIdx.x * 128;
  const int n0 = blockIdx.y * 128;
  __shared__ u16 As[128 * 64];
  __shared__ u16 Bs[128 * 64];
  const int t = threadIdx.x;
  const int lane = t & 63, wave = t >> 6;
  const int wm = (wave >> 1) * 64, wn = (wave & 1) * 64;
  f32x4 acc[4][4];
  #pragma unroll
  for (int m = 0; m < 4; m++)
    #pragma unroll
    for (int n = 0; n < 4; n++) acc[m][n] = (f32x4){0.f, 0.f, 0.f, 0.f};

  // staging: thread t, load j covers LDS bytes [t*16 + j*4096, +16)
  //   -> row = (t>>3) + j*32, phys slot = t&7, logical slot = (t&7) ^ (row&7)
  const int srow = t >> 3;
  const int sslot = (t & 7) ^ (srow & 7);
  const u16* Ag = hid + ((size_t)m0 + srow) * DIM_ + sslot * 8;
  const u16* Bg = Wt + (size_t)wsel * DIM_ * DIM_ + ((size_t)n0 + srow) * DIM_ + sslot * 8;
  u16* AsT = &As[t * 8];
  u16* BsT = &Bs[t * 8];
  const int lr = lane & 15, kg = lane >> 4;

  for (int k0 = 0; k0 < DIM_; k0 += 64) {
    #pragma unroll
    for (int j = 0; j < 4; j++) {
      gload_lds16(Ag + k0 + j * (32 * DIM_), AsT + j * 2048);
      gload_lds16(Bg + k0 + j * (32 * DIM_), BsT + j * 2048);
    }
    __syncthreads();
    #pragma unroll
    for (int ks = 0; ks < 2; ks++) {
      bf16x8 af[4], bfr[4];
      const int sw = ((ks * 4 + kg) ^ (lr & 7)) * 8;
      #pragma unroll
      for (int m = 0; m < 4; m++)
        af[m] = *reinterpret_cast<const bf16x8*>(&As[(wm + m * 16 + lr) * 64 + sw]);
      #pragma unroll
      for (int n = 0; n < 4; n++)
        bfr[n] = *reinterpret_cast<const bf16x8*>(&Bs[(wn + n * 16 + lr) * 64 + sw]);
      #pragma unroll
      for (int m = 0; m < 4; m++)
        #pragma unroll
        for (int n = 0; n < 4; n++)
          acc[m][n] = __builtin_amdgcn_mfma_f32_16x16x32_bf16(af[m], bfr[n], acc[m][n], 0, 0, 0);
    }
    __syncthreads();
  }

  const float* bias = (wsel == 0) ? bq : ((wsel == 1) ? bk : bv);
  u16* dst = (wsel == 0) ? qout : ((wsel == 1) ? kout : vout);
  const float scale = (wsel == 0) ? 0.125f : 1.0f;  // DH^-0.5
  const bool isv = (wsel == 2);
  const float s1 = isv ? 1.f : 0.5f, s2 = isv ? 1.f : 0.25f;
  const float s3 = isv ? 1.f : 0.125f, s4 = isv ? 1.f : 0.0625f;
  const int rg = lane >> 4;
  const int b = m0 >> 12;
  const int posb = m0 & (N_ - 1);
  const int h = (n0 + wn) >> 6;        // one head per wave (wn in {0,64})
  const size_t bh = (size_t)(b * H_ + h);

  #pragma unroll
  for (int m = 0; m < 4; m++) {
    const int plm = wm + m * 16;       // fragment pos base (multiple of 16)
    #pragma unroll
    for (int n = 0; n < 4; n++) {
      const int d = n * 16 + lr;
      const float bias_v = bias[n0 + wn + d];
      float v0 = (acc[m][n][0] + bias_v) * scale;
      float v1 = (acc[m][n][1] + bias_v) * scale;
      float v2 = (acc[m][n][2] + bias_v) * scale;
      float v3 = (acc[m][n][3] + bias_v) * scale;
      const int pl = plm + rg * 4;
      // L0
      size_t r0 = (bh * N_ + posb + pl) * 64 + d;
      dst[r0] = f2bf(v0); dst[r0 + 64] = f2bf(v1);
      dst[r0 + 128] = f2bf(v2); dst[r0 + 192] = f2bf(v3);
      // L1: row pairs, in-lane
      float c1a = v0 + v1, c1b = v2 + v3;
      size_t r1 = ((size_t)RB1 + bh * 2048 + (size_t)((posb + pl) >> 1)) * 64 + d;
      dst[r1] = f2bf(c1a * s1);
      dst[r1 + 64] = f2bf(c1b * s1);
      // L2: 4-row group, in-lane
      float c2 = c1a + c1b;
      dst[((size_t)RB2 + bh * 1024 + (size_t)((posb + pl) >> 2)) * 64 + d] = f2bf(c2 * s2);
      // L3: 8 rows (rg pair via shfl), L4: 16 rows
      float c3 = c2 + __shfl_xor(c2, 16);
      float c4 = c3 + __shfl_xor(c3, 32);
      if ((rg & 1) == 0)
        dst[((size_t)RB3 + bh * 512 + (size_t)(((posb + plm) >> 3) + (rg >> 1))) * 64 + d] =
            f2bf(c3 * s3);
      if (rg == 0)
        dst[((size_t)RB4 + bh * 256 + (size_t)((posb + plm) >> 4)) * 64 + d] = f2bf(c4 * s4);
    }
  }
}

// ---------------- coarsen pass 2: levels 5..6 from level 4 ----------------
__global__ __launch_bounds__(256) void k_coarsen56(u16* __restrict__ qb, u16* __restrict__ kb,
                                                   u16* __restrict__ vb) {
  int t = blockIdx.x * 256 + threadIdx.x;  // 3*64*64*8 = 98304
  int dg = t & 7;
  int p6 = (t >> 3) & 63;
  int bh = (t >> 9) & 63;
  int z = t >> 15;
  u16* buf = (z == 0) ? qb : ((z == 1) ? kb : vb);
  const bool isv = (z == 2);
  const float s5 = isv ? 1.f : 0.5f, s6 = isv ? 1.f : 0.25f;
  const u16* src = buf + ((size_t)RB4 + bh * 256 + p6 * 4) * 64 + dg * 8;
  float a5[8], a6[8];
  #pragma unroll
  for (int e = 0; e < 8; e++) { a5[e] = 0.f; a6[e] = 0.f; }
  #pragma unroll
  for (int i = 0; i < 4; i++) {
    u16x8 x = *reinterpret_cast<const u16x8*>(src + (size_t)i * 64);
    #pragma unroll
    for (int e = 0; e < 8; e++) a5[e] += bf2f(x[e]);
    if ((i & 1) == 1) {
      u16x8 o;
      #pragma unroll
      for (int e = 0; e < 8; e++) { o[e] = f2bf(a5[e] * s5); a6[e] += a5[e]; a5[e] = 0.f; }
      *reinterpret_cast<u16x8*>(buf + ((size_t)RB5 + bh * 128 + p6 * 2 + (i >> 1)) * 64 + dg * 8) = o;
    }
  }
  u16x8 o;
  #pragma unroll
  for (int e = 0; e < 8; e++) o[e] = f2bf(a6[e] * s6);
  *reinterpret_cast<u16x8*>(buf + ((size_t)RB6 + bh * 64 + p6) * 64 + dg * 8) = o;
}

// ---------------- shared attention core: S = q . K^T (16), A = exp(S - max) ----------------
__device__ __forceinline__ void block_scores(const u16* __restrict__ qp,
                                             const u16* __restrict__ kp,
                                             float* A, float& asum) {
  u16x8 q8[8];
  #pragma unroll
  for (int j = 0; j < 8; j++) q8[j] = *reinterpret_cast<const u16x8*>(qp + j * 8);
  float mx = -3.4e38f;
  #pragma unroll
  for (int c = 0; c < 16; c++) {
    float s = 0.f;
    #pragma unroll
    for (int j = 0; j < 8; j++) {
      u16x8 k8 = *reinterpret_cast<const u16x8*>(kp + c * 64 + j * 8);
      #pragma unroll
      for (int e = 0; e < 8; e++) s += bf2f(q8[j][e]) * bf2f(k8[e]);
    }
    A[c] = s;
    mx = fmaxf(mx, s);
  }
  asum = 0.f;
  #pragma unroll
  for (int c = 0; c < 16; c++) { A[c] = __expf(A[c] - mx); asum += A[c]; }
}

// ---------------- attention levels 1..6, one launch ----------------
__global__ __launch_bounds__(256) void k_attn_rest(
    const u16* __restrict__ qb, const u16* __restrict__ kb, const u16* __restrict__ vb,
    u16* __restrict__ Yb, float* __restrict__ Ab) {
  int gid = blockIdx.x * 256 + threadIdx.x;  // 258048 = 1008*256 exactly
  int r = gid, lnl = 11;
  while (r >= (64 << lnl)) { r -= (64 << lnl); --lnl; }
  int pos = r & ((1 << lnl) - 1);
  size_t row = (size_t)RB1 + gid;
  size_t kvrow = row - pos + ((((pos >> 4) ^ 1) & ((1 << (lnl - 4)) - 1)) << 4);

  float A[16], asum;
  block_scores(qb + row * 64, kb + kvrow * 64, A, asum);
  Ab[gid] = asum;

  const u16* vp = vb + kvrow * 64;
  u16* yp = Yb + (size_t)gid * 64;
  #pragma unroll
  for (int d0 = 0; d0 < 64; d0 += 16) {
    float y[16];
    #pragma unroll
    for (int e = 0; e < 16; e++) y[e] = 0.f;
    #pragma unroll
    for (int c = 0; c < 16; c++) {
      u16x8 v0 = *reinterpret_cast<const u16x8*>(vp + c * 64 + d0);
      u16x8 v1 = *reinterpret_cast<const u16x8*>(vp + c * 64 + d0 + 8);
      float a = A[c];
      #pragma unroll
      for (int e = 0; e < 8; e++) { y[e] += a * bf2f(v0[e]); y[8 + e] += a * bf2f(v1[e]); }
    }
    u16x8 o0, o1;
    #pragma unroll
    for (int e = 0; e < 8; e++) { o0[e] = f2bf(y[e]); o1[e] = f2bf(y[8 + e]); }
    *reinterpret_cast<u16x8*>(yp + d0) = o0;
    *reinterpret_cast<u16x8*>(yp + d0 + 8) = o1;
  }
}

// ---------------- attention level 0 fused with combine ----------------
__global__ __launch_bounds__(256) void k_attn0(
    const u16* __restrict__ qb, const u16* __restrict__ kb, const u16* __restrict__ vb,
    const u16* __restrict__ Yb, const float* __restrict__ Ab, float* __restrict__ out) {
  int gid = blockIdx.x * 256 + threadIdx.x;  // 262144 = 1024*256
  int bh = gid >> 12, pos = gid & 4095;
  size_t row = (size_t)gid;
  size_t kvrow = row - (pos & 15);  // level 0: diagonal block

  float A[16], asum;
  block_scores(qb + row * 64, kb + kvrow * 64, A, asum);

  float den = asum + 1e-8f;
  int ybase[6];
  #pragma unroll
  for (int l = 1; l <= 6; l++) {
    int s = 262144 - (262144 >> (l - 1));  // packed level-l segment start
    int idx = s + (bh << (12 - l)) + (pos >> l);
    den += Ab[idx];
    ybase[l - 1] = idx;
  }
  float inv = 1.0f / den;

  int b = bh >> 4, h = bh & 15;
  float* op = out + ((size_t)(b * N_ + pos)) * DIM_ + h * 64;
  const u16* vp = vb + kvrow * 64;
  #pragma unroll
  for (int d0 = 0; d0 < 64; d0 += 16) {
    float y[16];
    #pragma unroll
    for (int e = 0; e < 16; e++) y[e] = 0.f;
    #pragma unroll
    for (int c = 0; c < 16; c++) {
      u16x8 v0 = *reinterpret_cast<const u16x8*>(vp + c * 64 + d0);
      u16x8 v1 = *reinterpret_cast<const u16x8*>(vp + c * 64 + d0 + 8);
      float a = A[c];
      #pragma unroll
      for (int e = 0; e < 8; e++) { y[e] += a * bf2f(v0[e]); y[8 + e] += a * bf2f(v1[e]); }
    }
    #pragma unroll
    for (int l = 0; l < 6; l++) {
      const u16* yq = Yb + (size_t)ybase[l] * 64 + d0;
      u16x8 c0 = *reinterpret_cast<const u16x8*>(yq);
      u16x8 c1 = *reinterpret_cast<const u16x8*>(yq + 8);
      #pragma unroll
      for (int e = 0; e < 8; e++) { y[e] += bf2f(c0[e]); y[8 + e] += bf2f(c1[e]); }
    }
    f32x4 w0, w1, w2, w3;
    #pragma unroll
    for (int e = 0; e < 4; e++) {
      w0[e] = y[e] * inv; w1[e] = y[4 + e] * inv;
      w2[e] = y[8 + e] * inv; w3[e] = y[12 + e] * inv;
    }
    *reinterpret_cast<f32x4*>(op + d0) = w0;
    *reinterpret_cast<f32x4*>(op + d0 + 4) = w1;
    *reinterpret_cast<f32x4*>(op + d0 + 8) = w2;
    *reinterpret_cast<f32x4*>(op + d0 + 12) = w3;
  }
}

extern "C" void kernel_launch(void* const* d_in, const int* in_sizes, int n_in,
                              void* d_out, int out_size, void* d_ws, size_t ws_size,
                              hipStream_t stream) {
  const float* hid = (const float*)d_in[0];
  const float* Wq = (const float*)d_in[1];
  const float* bq = (const float*)d_in[2];
  const float* Wk = (const float*)d_in[3];
  const float* bk = (const float*)d_in[4];
  const float* Wv = (const float*)d_in[5];
  const float* bv = (const float*)d_in[6];
  float* out = (float*)d_out;
  char* ws = (char*)d_ws;

  // workspace (high-water 239,599,616 B):
  //   phase 1 (GEMM):  hidb [0, 33554432)   Wt [33554432, 39845888)
  //   phase 2 (attn):  Yb   [0, 33030144)   Ab [33030144, 34062336)   <- aliases dead hidb/Wt
  //   both:            qb [39845888) kb [106430464) vb [173015040) .. 239599616
  u16* hidb = (u16*)(ws + 0);
  u16* Wt   = (u16*)(ws + 33554432);
  u16* Yb   = (u16*)(ws + 0);           // bf16, levels 1..6 packed (258048 rows x 64)
  float* Ab = (float*)(ws + 33030144);  // fp32, levels 1..6 packed (258048)
  u16* qb   = (u16*)(ws + 39845888);
  u16* kb   = (u16*)(ws + 106430464);
  u16* vb   = (u16*)(ws + 173015040);

  k_hid2bf<<<16384, 256, 0, stream>>>(hid, hidb, MTOK * DIM_ / 4);
  k_transpose<<<dim3(32, 32, 3), dim3(32, 8, 1), 0, stream>>>(Wq, Wk, Wv, Wt);
  k_qkv_gemm<<<dim3(128, 8, 3), 256, 0, stream>>>(hidb, Wt, bq, bk, bv, qb, kb, vb);
  k_coarsen56<<<384, 256, 0, stream>>>(qb, kb, vb);
  k_attn_rest<<<1008, 256, 0, stream>>>(qb, kb, vb, Yb, Ab);
  k_attn0<<<1024, 256, 0, stream>>>(qb, kb, vb, Yb, Ab, out);
}